// Round 3
// baseline (834.108 us; speedup 1.0000x reference)
//
#include <hip/hip_runtime.h>
#include <hip/hip_bf16.h>
#include <math.h>

// Problem constants (fixed by the reference setup)
#define XT      1000000   // items
#define DQ      128       // dims
#define BQ      256       // queries
#define TI      64        // items per K1 tile (XT = 64 * 15625 exactly)
#define NTILES  15625
#define TPB     16        // tiles per block
#define NBLK    977       // ceil(NTILES/TPB)
#define CHUNK   16        // items per max-chunk
#define NCH     62500     // XT / CHUNK
#define MSTRIDE 62528     // padded M row stride (bf16 elems, 16B-aligned rows)
#define CAP     256       // max chunks rescored per query
#define NCAND   (CAP * CHUNK)  // 4096
#define KTOP    100
#define DELTA   0.5f      // covers bf16 filter error with margin (validated r1/r2)
#define ZLO     3.0f      // histogram band lower edge (in units of ||q||)
#define BINS    512
#define BINW    0.005f

typedef float f32x4 __attribute__((ext_vector_type(4)));
typedef short bf16x8 __attribute__((ext_vector_type(8)));

// ---- order-preserving float<->uint packing: (score desc, id asc) as one u64 ----
__device__ __forceinline__ unsigned ordf(float f) {
  unsigned u = __float_as_uint(f);
  return (u & 0x80000000u) ? ~u : (u ^ 0x80000000u);
}
__device__ __forceinline__ float unordf(unsigned k) {
  unsigned bits = (k & 0x80000000u) ? (k ^ 0x80000000u) : ~k;
  return __uint_as_float(bits);
}
__device__ __forceinline__ unsigned long long packkv(float v, unsigned id) {
  return ((unsigned long long)ordf(v) << 32) | (unsigned long long)(~id);
}
__device__ __forceinline__ float pk_val(unsigned long long e) { return unordf((unsigned)(e >> 32)); }
__device__ __forceinline__ unsigned pk_id(unsigned long long e) { return ~(unsigned)(e & 0xFFFFFFFFu); }

__device__ __forceinline__ unsigned short f2bf(float f) {  // RNE fp32->bf16
  unsigned u = __float_as_uint(f);
  u += 0x7FFFu + ((u >> 16) & 1u);
  return (unsigned short)(u >> 16);
}
// HW packed RNE convert: lo16 = bf16(a), hi16 = bf16(b)
__device__ __forceinline__ unsigned cvt_pk_bf16(float a, float b) {
  unsigned r;
  asm("v_cvt_pk_bf16_f32 %0, %1, %2" : "=v"(r) : "v"(a), "v"(b));
  return r;
}
__device__ __forceinline__ float bf_to_f(unsigned us) {
  return __uint_as_float(us << 16);
}

// ---- in-LDS bitonic sort, ascending, N power of two ----
template <int N>
__device__ void bitonic_sort(unsigned long long* buf) {
  for (int k = 2; k <= N; k <<= 1) {
    for (int j = k >> 1; j > 0; j >>= 1) {
      for (int e = threadIdx.x; e < N; e += blockDim.x) {
        int p = e ^ j;
        if (p > e) {
          unsigned long long a = buf[e], b = buf[p];
          bool up = ((e & k) == 0);
          if (up ? (a > b) : (a < b)) { buf[e] = b; buf[p] = a; }
        }
      }
      __syncthreads();
    }
  }
}

// =================== P0: Q fp32 -> bf16 + per-query norms ===================
__global__ void p0_qprep(const float* __restrict__ Q, unsigned short* __restrict__ Qp,
                         float* __restrict__ norms) {
  const int q = blockIdx.x, d = threadIdx.x;  // 128 threads
  float v = Q[q * DQ + d];
  Qp[q * DQ + d] = f2bf(v);
  float ss = v * v;
#pragma unroll
  for (int m = 1; m < 64; m <<= 1) ss += __shfl_xor(ss, m);
  __shared__ float part[2];
  if ((d & 63) == 0) part[d >> 6] = ss;
  __syncthreads();
  if (d == 0) norms[q] = sqrtf(part[0] + part[1]);
}

// =================== K1: pipelined bf16 MFMA filter ===================
// 256 thr = 4 waves. Tile: 256 q x 64 items, full K=128 staged in LDS (bf16).
// Wave w covers queries [w*64, w*64+64), all 64 items. A = items, B = queries:
// C row = item, col = query -> chunk max = 3 reg-fmax + shfl_xor(16,32).
// Xs swizzle: byte ^= slot(x)<<4, slot = ((x>>2)&3)<<1 | (x&1)  (validated r2)
__device__ __forceinline__ unsigned xs_off(int x, int d) {
  unsigned byte = (unsigned)(x * 256 + d * 2);
  unsigned slot = (unsigned)((((x >> 2) & 3) << 1) | (x & 1));
  return byte ^ (slot << 4);
}

__global__ __launch_bounds__(256, 4) void k1_filter(
    const unsigned short* __restrict__ Qp, const float* __restrict__ It,
    unsigned short* __restrict__ M) {
  __shared__ unsigned Xs32[4096];                       // 16 KB: [64 x][128 d] bf16 swizzled
  __shared__ __align__(16) unsigned short Ms4[256][40]; // 20 KB: [q][32 chunk maxima + pad]
  const int t = threadIdx.x;
  const int xg = (t & 15) * 4;          // item quad within tile
  const int dbase = (t >> 4) * 8;       // 8 consecutive d rows per thread
  const int l = t & 63, w = t >> 6;
  const int wq = w * 64;                // wave's query base
  const int lm = l & 15, h = l >> 4;
  const int tile0 = blockIdx.x * TPB;

  float4 st[8];
  {  // prologue: issue loads for tile0
    int x0 = tile0 * TI;
    bool ok = (x0 < XT);
#pragma unroll
    for (int r = 0; r < 8; ++r)
      st[r] = ok ? *(const float4*)&It[(size_t)(dbase + r) * XT + x0 + xg]
                 : make_float4(0.f, 0.f, 0.f, 0.f);
  }

  for (int tt = 0; tt < TPB; ++tt) {
    // ---- convert staged regs -> Xs (bf16, swizzled) ----
#pragma unroll
    for (int rp = 0; rp < 4; ++rp) {
      int d0 = dbase + rp * 2;
      float a0[4] = {st[rp * 2].x, st[rp * 2].y, st[rp * 2].z, st[rp * 2].w};
      float a1[4] = {st[rp * 2 + 1].x, st[rp * 2 + 1].y, st[rp * 2 + 1].z, st[rp * 2 + 1].w};
#pragma unroll
      for (int j = 0; j < 4; ++j)
        Xs32[xs_off(xg + j, d0) >> 2] = cvt_pk_bf16(a0[j], a1[j]);
    }
    // ---- issue loads for next tile (overlaps with MFMA below) ----
    if (tt + 1 < TPB) {
      int x0 = (tile0 + tt + 1) * TI;
      bool ok = (x0 < XT);
#pragma unroll
      for (int r = 0; r < 8; ++r)
        st[r] = ok ? *(const float4*)&It[(size_t)(dbase + r) * XT + x0 + xg]
                   : make_float4(0.f, 0.f, 0.f, 0.f);
    }
    __syncthreads();

    // ---- MFMA: A = items (LDS), B = queries (global, L2-hot) ----
    f32x4 acc[4][4];
#pragma unroll
    for (int a = 0; a < 4; ++a)
#pragma unroll
      for (int b = 0; b < 4; ++b) acc[a][b] = (f32x4){0.f, 0.f, 0.f, 0.f};

#pragma unroll
    for (int n = 0; n < 4; ++n) {
      bf16x8 afr[4];
#pragma unroll
      for (int a = 0; a < 4; ++a)
        afr[a] = *(const bf16x8*)((const char*)Xs32 + xs_off(a * 16 + lm, n * 32 + h * 8));
#pragma unroll
      for (int b = 0; b < 4; ++b) {
        bf16x8 bfr = *(const bf16x8*)&Qp[(size_t)(wq + b * 16 + lm) * DQ + n * 32 + h * 8];
#pragma unroll
        for (int a = 0; a < 4; ++a)
          acc[a][b] = __builtin_amdgcn_mfma_f32_16x16x32_bf16(afr[a], bfr, acc[a][b], 0, 0, 0);
      }
    }

    // ---- epilogue: per-(chunk a, query col) max into Ms4 ----
#pragma unroll
    for (int a = 0; a < 4; ++a)
#pragma unroll
      for (int b = 0; b < 4; ++b) {
        f32x4 v = acc[a][b];
        float m0 = fmaxf(fmaxf(v.x, v.y), fmaxf(v.z, v.w));
        m0 = fmaxf(m0, __shfl_xor(m0, 16));
        m0 = fmaxf(m0, __shfl_xor(m0, 32));
        if (l < 16)
          Ms4[wq + b * 16 + lm][(tt & 7) * 4 + a] = (unsigned short)(cvt_pk_bf16(m0, 0.f) & 0xffffu);
      }
    __syncthreads();

    // ---- flush 32 accumulated chunk maxima every 8 tiles ----
    if ((tt & 7) == 7) {
      int cb = (tile0 + tt - 7) * 4;  // 32-chunk group start
      // thread t handles query q = t: 64 B contiguous (full cache lines)
      uint4 v0 = *(const uint4*)&Ms4[t][0];
      uint4 v1 = *(const uint4*)&Ms4[t][8];
      uint4 v2 = *(const uint4*)&Ms4[t][16];
      uint4 v3 = *(const uint4*)&Ms4[t][24];
      unsigned short* dst = M + (size_t)t * MSTRIDE + cb;
      *(uint4*)(dst + 0) = v0;
      *(uint4*)(dst + 8) = v1;
      *(uint4*)(dst + 16) = v2;
      *(uint4*)(dst + 24) = v3;
      // cols >= NCH (block 976 only) carry exact 0.0 scores from zero-staged
      // items -> harmless, and they initialize the MSTRIDE pad for K2.
    }
  }
}

// =================== K2: histogram-select tau + ballot emit (no sorts) ===================
__global__ __launch_bounds__(256) void k2_select(
    const unsigned short* __restrict__ M, const float* __restrict__ norms,
    int* __restrict__ list, int* __restrict__ cnt_out) {
  const int q = blockIdx.x;
  const int t = threadIdx.x;
  const unsigned short* Mq = M + (size_t)q * MSTRIDE;
  __shared__ int hist[BINS];
  __shared__ float sThr;
  for (int b = t; b < BINS; b += 256) hist[b] = 0;
  if (t == 0) cnt_out[q] = 0;
  __syncthreads();
  const float norm = norms[q];
  const float invn = 1.0f / norm;
  const int NV = MSTRIDE / 8;  // 7816 vec8 per row

  // pass 1: histogram of z = v/||q|| over [ZLO, ZLO + BINS*BINW)
  for (int iv = t; iv < NV; iv += 256) {
    uint4 pk = *(const uint4*)(Mq + iv * 8);
    unsigned uu[4] = {pk.x, pk.y, pk.z, pk.w};
#pragma unroll
    for (int m = 0; m < 4; ++m) {
#pragma unroll
      for (int s = 0; s < 2; ++s) {
        float v = bf_to_f(s ? (uu[m] >> 16) : (uu[m] & 0xffffu));
        float z = v * invn;
        if (z >= ZLO) {
          int bin = (int)((z - ZLO) * (1.0f / BINW));
          if (bin > BINS - 1) bin = BINS - 1;
          atomicAdd(&hist[bin], 1);
        }
      }
    }
  }
  __syncthreads();
  if (t == 0) {
    int cum = 0, bsel = 0;
    for (int b = BINS - 1; b >= 0; --b) {
      cum += hist[b];
      if (cum >= KTOP) { bsel = b; break; }
    }
    // lower bound on 100th-largest chunk max (-1 bin for float-rounding slack)
    float tlo = (ZLO + (float)(bsel - 1) * BINW) * norm;
    sThr = tlo - DELTA;
  }
  __syncthreads();
  const float thr = sThr;
  const int lane = t & 63;

  // pass 2: emit chunk ids with max >= thr (wave-aggregated atomics)
  for (int iv = t; iv < NV; iv += 256) {
    uint4 pk = *(const uint4*)(Mq + iv * 8);
    unsigned uu[4] = {pk.x, pk.y, pk.z, pk.w};
#pragma unroll
    for (int m = 0; m < 4; ++m) {
#pragma unroll
      for (int s = 0; s < 2; ++s) {
        float v = bf_to_f(s ? (uu[m] >> 16) : (uu[m] & 0xffffu));
        bool pred = (v >= thr);
        unsigned long long mm = __ballot(pred);
        if (mm) {
          int leader = __ffsll((unsigned long long)mm) - 1;
          int base = 0;
          if (lane == leader) base = atomicAdd(&cnt_out[q], (int)__popcll(mm));
          base = __shfl(base, leader);
          if (pred) {
            int pos = base + (int)__popcll(mm & ((1ULL << lane) - 1ULL));
            if (pos < CAP) list[q * CAP + pos] = iv * 8 + m * 2 + s;
          }
        }
      }
    }
  }
}

// =================== K3: EXACT fp32 rescore of listed chunks (unchanged math) ===================
__global__ __launch_bounds__(256) void k3_rescore(
    const float* __restrict__ Q, const float* __restrict__ It,
    const int* __restrict__ list, const int* __restrict__ cnt_in,
    unsigned long long* __restrict__ cand) {
  const int q = blockIdx.x >> 4;
  const int sg = blockIdx.x & 15;
  __shared__ float qv[DQ];
  if (threadIdx.x < DQ) qv[threadIdx.x] = Q[q * DQ + threadIdx.x];
  __syncthreads();
  const int s = threadIdx.x >> 4;
  const int it = threadIdx.x & 15;
  const int gs = sg * 16 + s;
  int n = cnt_in[q];
  if (n > CAP) n = CAP;
  unsigned long long out = 0ULL;
  if (gs < n) {
    const int chunk = list[q * CAP + gs];
    const int x = chunk * CHUNK + it;
    float a = 0.f;
#pragma unroll 8
    for (int d = 0; d < DQ; ++d) a = fmaf(qv[d], It[(size_t)d * XT + x], a);
    out = packkv(a, (unsigned)x);
  }
  cand[(size_t)q * NCAND + gs * CHUNK + it] = out;
}

// =================== K4: final per-query top-100 ===================
__global__ __launch_bounds__(512) void k4_final(
    const unsigned long long* __restrict__ cand, float* __restrict__ out) {
  const int q = blockIdx.x;
  __shared__ unsigned long long buf[NCAND];
  for (int s = threadIdx.x; s < NCAND; s += blockDim.x) buf[s] = cand[(size_t)q * NCAND + s];
  __syncthreads();
  bitonic_sort<NCAND>(buf);
  for (int r = threadIdx.x; r < KTOP; r += blockDim.x) {
    unsigned long long e = buf[NCAND - 1 - r];
    out[q * KTOP + r] = pk_val(e);                       // topk_logits
    out[BQ * KTOP + q * KTOP + r] = (float)pk_id(e);     // topk_item_ids
  }
}

extern "C" void kernel_launch(void* const* d_in, const int* in_sizes, int n_in,
                              void* d_out, int out_size, void* d_ws, size_t ws_size,
                              hipStream_t stream) {
  const float* Q = (const float*)d_in[0];   // [256,128]
  const float* It = (const float*)d_in[1];  // [128,1000000]
  float* out = (float*)d_out;               // [25600 logits][25600 ids]
  char* ws = (char*)d_ws;
  // ws layout (bytes):
  //   M     : 0          .. 32,014,336   (256 x 62528 bf16)
  //   list  : 32,014,336 .. +262,144
  //   cnt   : 32,276,480 .. +1,024
  //   norms : 32,277,504 .. +1,024
  //   Qp    : 32,278,528 .. +65,536
  //   cand  : 33,554,432 .. +8,388,608
  unsigned short* M = (unsigned short*)ws;
  int* list = (int*)(ws + 32014336);
  int* cnt = (int*)(ws + 32276480);
  float* norms = (float*)(ws + 32277504);
  unsigned short* Qp = (unsigned short*)(ws + 32278528);
  unsigned long long* cand = (unsigned long long*)(ws + 33554432);

  p0_qprep<<<dim3(BQ), dim3(DQ), 0, stream>>>(Q, Qp, norms);
  k1_filter<<<dim3(NBLK), dim3(256), 0, stream>>>(Qp, It, M);
  k2_select<<<dim3(BQ), dim3(256), 0, stream>>>(M, norms, list, cnt);
  k3_rescore<<<dim3(BQ * 16), dim3(256), 0, stream>>>(Q, It, list, cnt, cand);
  k4_final<<<dim3(BQ), dim3(512), 0, stream>>>(cand, out);
}

// Round 4
// 805.373 us; speedup vs baseline: 1.0357x; 1.0357x over previous
//
#include <hip/hip_runtime.h>
#include <hip/hip_bf16.h>
#include <math.h>

// Problem constants (fixed by the reference setup)
#define XT      1000000   // items
#define DQ      128       // dims
#define BQ      256       // queries
#define TI      64        // items per K1 tile (XT = 64 * 15625 exactly)
#define NTILES  15625
#define TPB     16        // tiles per block
#define NBLK    977       // ceil(NTILES/TPB); 977*64 chunks = 62528 rows
#define CHUNK   16        // items per max-chunk
#define NCH     62500     // XT / CHUNK
#define NCHP    62528     // padded chunk rows (NBLK * 64)
#define CAP     256       // max chunks rescored per query
#define NCAND   (CAP * CHUNK)  // 4096
#define KTOP    100
#define DELTA   0.5f      // covers bf16 filter error with margin (validated r1-r3)
#define ZLO     3.0f      // histogram band lower edge (in units of ||q||)
#define BINS    512
#define BINW    0.005f

typedef float f32x4 __attribute__((ext_vector_type(4)));
typedef short bf16x8 __attribute__((ext_vector_type(8)));

// ---- order-preserving float<->uint packing: (score desc, id asc) as one u64 ----
__device__ __forceinline__ unsigned ordf(float f) {
  unsigned u = __float_as_uint(f);
  return (u & 0x80000000u) ? ~u : (u ^ 0x80000000u);
}
__device__ __forceinline__ float unordf(unsigned k) {
  unsigned bits = (k & 0x80000000u) ? (k ^ 0x80000000u) : ~k;
  return __uint_as_float(bits);
}
__device__ __forceinline__ unsigned long long packkv(float v, unsigned id) {
  return ((unsigned long long)ordf(v) << 32) | (unsigned long long)(~id);
}
__device__ __forceinline__ float pk_val(unsigned long long e) { return unordf((unsigned)(e >> 32)); }
__device__ __forceinline__ unsigned pk_id(unsigned long long e) { return ~(unsigned)(e & 0xFFFFFFFFu); }

__device__ __forceinline__ unsigned short f2bf(float f) {  // RNE fp32->bf16
  unsigned u = __float_as_uint(f);
  u += 0x7FFFu + ((u >> 16) & 1u);
  return (unsigned short)(u >> 16);
}
// HW packed RNE convert: lo16 = bf16(a), hi16 = bf16(b)
__device__ __forceinline__ unsigned cvt_pk_bf16(float a, float b) {
  unsigned r;
  asm("v_cvt_pk_bf16_f32 %0, %1, %2" : "=v"(r) : "v"(a), "v"(b));
  return r;
}
__device__ __forceinline__ float bf_to_f(unsigned us) {
  return __uint_as_float(us << 16);
}

// ---- in-LDS bitonic sort, ascending, N power of two ----
template <int N>
__device__ void bitonic_sort(unsigned long long* buf) {
  for (int k = 2; k <= N; k <<= 1) {
    for (int j = k >> 1; j > 0; j >>= 1) {
      for (int e = threadIdx.x; e < N; e += blockDim.x) {
        int p = e ^ j;
        if (p > e) {
          unsigned long long a = buf[e], b = buf[p];
          bool up = ((e & k) == 0);
          if (up ? (a > b) : (a < b)) { buf[e] = b; buf[p] = a; }
        }
      }
      __syncthreads();
    }
  }
}

// =================== P0: Q fp32 -> bf16 + per-query norms ===================
__global__ void p0_qprep(const float* __restrict__ Q, unsigned short* __restrict__ Qp,
                         float* __restrict__ norms) {
  const int q = blockIdx.x, d = threadIdx.x;  // 128 threads
  float v = Q[q * DQ + d];
  Qp[q * DQ + d] = f2bf(v);
  float ss = v * v;
#pragma unroll
  for (int m = 1; m < 64; m <<= 1) ss += __shfl_xor(ss, m);
  __shared__ float part[2];
  if ((d & 63) == 0) part[d >> 6] = ss;
  __syncthreads();
  if (d == 0) norms[q] = sqrtf(part[0] + part[1]);
}

// =================== K1: pipelined bf16 MFMA filter ===================
// 256 thr = 4 waves. Tile: 256 q x 64 items, full K=128 staged in LDS (bf16).
// Wave w covers queries [w*64, w*64+64), all 64 items. A = items, B = queries:
// C row = item, col = query -> chunk max = 3 reg-fmax + shfl_xor(16,32).
// M is CHUNK-MAJOR [NCHP][256]: each block flushes 16 KB contiguous (coalesced).
__device__ __forceinline__ unsigned xs_off(int x, int d) {
  unsigned byte = (unsigned)(x * 256 + d * 2);
  unsigned slot = (unsigned)((((x >> 2) & 3) << 1) | (x & 1));
  return byte ^ (slot << 4);
}

__global__ __launch_bounds__(256, 4) void k1_filter(
    const unsigned short* __restrict__ Qp, const float* __restrict__ It,
    unsigned short* __restrict__ M) {
  __shared__ unsigned Xs32[4096];                        // 16 KB: [64 x][128 d] bf16 swizzled
  __shared__ __align__(16) unsigned short Ms[32][256];   // 16 KB: [chunk-local][query]
  const int t = threadIdx.x;
  const int xg = (t & 15) * 4;          // item quad within tile
  const int dbase = (t >> 4) * 8;       // 8 consecutive d rows per thread
  const int l = t & 63, w = t >> 6;
  const int wq = w * 64;                // wave's query base
  const int lm = l & 15, h = l >> 4;
  const int tile0 = blockIdx.x * TPB;

  float4 st[8];
  {  // prologue: issue loads for tile0
    int x0 = tile0 * TI;
    bool ok = (x0 < XT);
#pragma unroll
    for (int r = 0; r < 8; ++r)
      st[r] = ok ? *(const float4*)&It[(size_t)(dbase + r) * XT + x0 + xg]
                 : make_float4(0.f, 0.f, 0.f, 0.f);
  }

  for (int tt = 0; tt < TPB; ++tt) {
    // ---- convert staged regs -> Xs (bf16, swizzled) ----
#pragma unroll
    for (int rp = 0; rp < 4; ++rp) {
      int d0 = dbase + rp * 2;
      float a0[4] = {st[rp * 2].x, st[rp * 2].y, st[rp * 2].z, st[rp * 2].w};
      float a1[4] = {st[rp * 2 + 1].x, st[rp * 2 + 1].y, st[rp * 2 + 1].z, st[rp * 2 + 1].w};
#pragma unroll
      for (int j = 0; j < 4; ++j)
        Xs32[xs_off(xg + j, d0) >> 2] = cvt_pk_bf16(a0[j], a1[j]);
    }
    // ---- issue loads for next tile (overlaps with MFMA below) ----
    if (tt + 1 < TPB) {
      int x0 = (tile0 + tt + 1) * TI;
      bool ok = (x0 < XT);
#pragma unroll
      for (int r = 0; r < 8; ++r)
        st[r] = ok ? *(const float4*)&It[(size_t)(dbase + r) * XT + x0 + xg]
                   : make_float4(0.f, 0.f, 0.f, 0.f);
    }
    __syncthreads();

    // ---- MFMA: A = items (LDS), B = queries (global, L2-hot) ----
    f32x4 acc[4][4];
#pragma unroll
    for (int a = 0; a < 4; ++a)
#pragma unroll
      for (int b = 0; b < 4; ++b) acc[a][b] = (f32x4){0.f, 0.f, 0.f, 0.f};

#pragma unroll
    for (int n = 0; n < 4; ++n) {
      bf16x8 afr[4];
#pragma unroll
      for (int a = 0; a < 4; ++a)
        afr[a] = *(const bf16x8*)((const char*)Xs32 + xs_off(a * 16 + lm, n * 32 + h * 8));
#pragma unroll
      for (int b = 0; b < 4; ++b) {
        bf16x8 bfr = *(const bf16x8*)&Qp[(size_t)(wq + b * 16 + lm) * DQ + n * 32 + h * 8];
#pragma unroll
        for (int a = 0; a < 4; ++a)
          acc[a][b] = __builtin_amdgcn_mfma_f32_16x16x32_bf16(afr[a], bfr, acc[a][b], 0, 0, 0);
      }
    }

    // ---- epilogue: per-(chunk a, query col) max into chunk-major Ms ----
#pragma unroll
    for (int a = 0; a < 4; ++a)
#pragma unroll
      for (int b = 0; b < 4; ++b) {
        f32x4 v = acc[a][b];
        float m0 = fmaxf(fmaxf(v.x, v.y), fmaxf(v.z, v.w));
        m0 = fmaxf(m0, __shfl_xor(m0, 16));
        m0 = fmaxf(m0, __shfl_xor(m0, 32));
        if (l < 16)
          Ms[(tt & 7) * 4 + a][wq + b * 16 + lm] =
              (unsigned short)(cvt_pk_bf16(m0, 0.f) & 0xffffu);
      }
    __syncthreads();

    // ---- flush 32 chunk rows (16 KB contiguous, fully coalesced) every 8 tiles ----
    if ((tt & 7) == 7) {
      const uint4* srcv = (const uint4*)&Ms[0][0];
      uint4* dstv = (uint4*)(M + ((size_t)tile0 * 4 + (size_t)(tt >> 3) * 32) * 256);
#pragma unroll
      for (int i = 0; i < 4; ++i) dstv[t + i * 256] = srcv[t + i * 256];
      // NOTE: no extra sync needed — next Ms writes happen after next tile's
      // mid-loop __syncthreads(), which orders them after this flush.
    }
  }
}

// =================== K2a: per-query histogram of chunk maxima (chunk-major reads) ===================
__global__ __launch_bounds__(256) void k2a_hist(
    const unsigned short* __restrict__ M, const float* __restrict__ norms,
    int* __restrict__ ghist) {
  const int t = threadIdx.x;
  __shared__ float s_invn[BQ];
  s_invn[t] = 1.0f / norms[t];
  __syncthreads();
  const uint4* src = (const uint4*)(M + (size_t)blockIdx.x * 64 * 256);
  for (int i = t; i < 2048; i += 256) {  // 64 chunk rows x 32 uint4
    uint4 v = src[i];
    const int q0 = (i & 31) * 8;
    unsigned uu[4] = {v.x, v.y, v.z, v.w};
#pragma unroll
    for (int m = 0; m < 4; ++m) {
#pragma unroll
      for (int s = 0; s < 2; ++s) {
        float val = bf_to_f(s ? (uu[m] >> 16) : (uu[m] & 0xffffu));
        int q = q0 + m * 2 + s;
        float z = val * s_invn[q];
        if (z >= ZLO) {
          int bin = (int)((z - ZLO) * (1.0f / BINW));
          if (bin > BINS - 1) bin = BINS - 1;
          atomicAdd(&ghist[q * BINS + bin], 1);
        }
      }
    }
  }
}

// =================== K2b: per-query threshold from histogram suffix-scan ===================
__global__ __launch_bounds__(512) void k2b_thr(
    const int* __restrict__ ghist, const float* __restrict__ norms,
    float* __restrict__ thrArr, int* __restrict__ cnt) {
  const int q = blockIdx.x, b = threadIdx.x;  // 512 threads = BINS
  __shared__ int sfx[BINS];
  sfx[b] = ghist[q * BINS + b];
  __syncthreads();
  for (int off = 1; off < BINS; off <<= 1) {  // suffix sum
    int v = (b + off < BINS) ? sfx[b + off] : 0;
    __syncthreads();
    sfx[b] += v;
    __syncthreads();
  }
  bool p = sfx[b] >= KTOP;
  bool pn = (b < BINS - 1) ? (sfx[b + 1] >= KTOP) : false;
  if (b == 0) {
    cnt[q] = 0;
    if (sfx[0] < KTOP) thrArr[q] = -3.0e38f;  // unreachable for this data; safety
  }
  if (p && !pn)  // unique boundary: b = largest bin with suffix >= KTOP
    thrArr[q] = (ZLO + (float)(b - 1) * BINW) * norms[q] - DELTA;
}

// =================== K2c: emit candidate chunks (chunk-major reads, sparse atomics) ===================
__global__ __launch_bounds__(256) void k2c_emit(
    const unsigned short* __restrict__ M, const float* __restrict__ thrArr,
    int* __restrict__ list, int* __restrict__ cnt) {
  const int t = threadIdx.x;
  __shared__ float s_thr[BQ];
  s_thr[t] = thrArr[t];
  __syncthreads();
  const int c0 = blockIdx.x * 64;
  const uint4* src = (const uint4*)(M + (size_t)c0 * 256);
  for (int i = t; i < 2048; i += 256) {
    uint4 v = src[i];
    const int q0 = (i & 31) * 8;
    const int c = c0 + (i >> 5);
    unsigned uu[4] = {v.x, v.y, v.z, v.w};
#pragma unroll
    for (int m = 0; m < 4; ++m) {
#pragma unroll
      for (int s = 0; s < 2; ++s) {
        float val = bf_to_f(s ? (uu[m] >> 16) : (uu[m] & 0xffffu));
        int q = q0 + m * 2 + s;
        if (val >= s_thr[q]) {
          int pos = atomicAdd(&cnt[q], 1);
          if (pos < CAP) list[q * CAP + pos] = c;
        }
      }
    }
  }
}

// =================== K3: EXACT fp32 rescore of listed chunks (unchanged math) ===================
__global__ __launch_bounds__(256) void k3_rescore(
    const float* __restrict__ Q, const float* __restrict__ It,
    const int* __restrict__ list, const int* __restrict__ cnt_in,
    unsigned long long* __restrict__ cand) {
  const int q = blockIdx.x >> 4;
  const int sg = blockIdx.x & 15;
  __shared__ float qv[DQ];
  if (threadIdx.x < DQ) qv[threadIdx.x] = Q[q * DQ + threadIdx.x];
  __syncthreads();
  const int s = threadIdx.x >> 4;
  const int it = threadIdx.x & 15;
  const int gs = sg * 16 + s;
  int n = cnt_in[q];
  if (n > CAP) n = CAP;
  unsigned long long out = 0ULL;
  if (gs < n) {
    const int chunk = list[q * CAP + gs];
    const int x = chunk * CHUNK + it;
    float a = 0.f;
#pragma unroll 8
    for (int d = 0; d < DQ; ++d) a = fmaf(qv[d], It[(size_t)d * XT + x], a);
    out = packkv(a, (unsigned)x);
  }
  cand[(size_t)q * NCAND + gs * CHUNK + it] = out;
}

// =================== K4: final per-query top-100 ===================
__global__ __launch_bounds__(512) void k4_final(
    const unsigned long long* __restrict__ cand, float* __restrict__ out) {
  const int q = blockIdx.x;
  __shared__ unsigned long long buf[NCAND];
  for (int s = threadIdx.x; s < NCAND; s += blockDim.x) buf[s] = cand[(size_t)q * NCAND + s];
  __syncthreads();
  bitonic_sort<NCAND>(buf);
  for (int r = threadIdx.x; r < KTOP; r += blockDim.x) {
    unsigned long long e = buf[NCAND - 1 - r];
    out[q * KTOP + r] = pk_val(e);                       // topk_logits
    out[BQ * KTOP + q * KTOP + r] = (float)pk_id(e);     // topk_item_ids
  }
}

extern "C" void kernel_launch(void* const* d_in, const int* in_sizes, int n_in,
                              void* d_out, int out_size, void* d_ws, size_t ws_size,
                              hipStream_t stream) {
  const float* Q = (const float*)d_in[0];   // [256,128]
  const float* It = (const float*)d_in[1];  // [128,1000000]
  float* out = (float*)d_out;               // [25600 logits][25600 ids]
  char* ws = (char*)d_ws;
  // ws layout (bytes):
  //   M      : 0          .. 32,014,336   (62528 x 256 bf16, CHUNK-MAJOR)
  //   ghist  : 32,014,336 .. +524,288     (256 x 512 int)
  //   thrArr : 32,538,624 .. +1,024
  //   list   : 32,539,648 .. +262,144
  //   cnt    : 32,801,792 .. +1,024
  //   norms  : 32,802,816 .. +1,024
  //   Qp     : 32,803,840 .. +65,536
  //   cand   : 33,554,432 .. +8,388,608
  unsigned short* M = (unsigned short*)ws;
  int* ghist = (int*)(ws + 32014336);
  float* thrArr = (float*)(ws + 32538624);
  int* list = (int*)(ws + 32539648);
  int* cnt = (int*)(ws + 32801792);
  float* norms = (float*)(ws + 32802816);
  unsigned short* Qp = (unsigned short*)(ws + 32803840);
  unsigned long long* cand = (unsigned long long*)(ws + 33554432);

  hipMemsetAsync(ghist, 0, BQ * BINS * sizeof(int), stream);
  p0_qprep<<<dim3(BQ), dim3(DQ), 0, stream>>>(Q, Qp, norms);
  k1_filter<<<dim3(NBLK), dim3(256), 0, stream>>>(Qp, It, M);
  k2a_hist<<<dim3(NBLK), dim3(256), 0, stream>>>(M, norms, ghist);
  k2b_thr<<<dim3(BQ), dim3(512), 0, stream>>>(ghist, norms, thrArr, cnt);
  k2c_emit<<<dim3(NBLK), dim3(256), 0, stream>>>(M, thrArr, list, cnt);
  k3_rescore<<<dim3(BQ * 16), dim3(256), 0, stream>>>(Q, It, list, cnt, cand);
  k4_final<<<dim3(BQ), dim3(512), 0, stream>>>(cand, out);
}

// Round 5
// 469.676 us; speedup vs baseline: 1.7759x; 1.7147x over previous
//
#include <hip/hip_runtime.h>
#include <hip/hip_bf16.h>
#include <math.h>

// Problem constants (fixed by the reference setup)
#define XT      1000000   // items
#define DQ      128       // dims
#define BQ      256       // queries
#define TI      64        // items per K1 tile (XT = 64 * 15625 exactly)
#define NTILES  15625
#define TPB     16        // tiles per block
#define NBLK    977       // ceil(NTILES/TPB); 977*64 chunks = 62528 rows
#define CHUNK   16        // items per max-chunk
#define NCH     62500     // XT / CHUNK
#define NCHP    62528     // padded chunk rows (NBLK * 64)
#define CAP     256       // max chunks rescored per query
#define NCAND   (CAP * CHUNK)  // 4096
#define KTOP    100
#define DELTA   0.5f      // covers bf16 filter error with margin (validated r1-r4)
#define ZLO     3.0f      // histogram band lower edge (in units of ||q||)
#define BINS    512
#define BINW    0.005f

typedef float f32x4 __attribute__((ext_vector_type(4)));
typedef short bf16x8 __attribute__((ext_vector_type(8)));

// ---- order-preserving float<->uint packing: (score desc, id asc) as one u64 ----
__device__ __forceinline__ unsigned ordf(float f) {
  unsigned u = __float_as_uint(f);
  return (u & 0x80000000u) ? ~u : (u ^ 0x80000000u);
}
__device__ __forceinline__ float unordf(unsigned k) {
  unsigned bits = (k & 0x80000000u) ? (k ^ 0x80000000u) : ~k;
  return __uint_as_float(bits);
}
__device__ __forceinline__ unsigned long long packkv(float v, unsigned id) {
  return ((unsigned long long)ordf(v) << 32) | (unsigned long long)(~id);
}
__device__ __forceinline__ float pk_val(unsigned long long e) { return unordf((unsigned)(e >> 32)); }
__device__ __forceinline__ unsigned pk_id(unsigned long long e) { return ~(unsigned)(e & 0xFFFFFFFFu); }

__device__ __forceinline__ unsigned short f2bf(float f) {  // RNE fp32->bf16
  unsigned u = __float_as_uint(f);
  u += 0x7FFFu + ((u >> 16) & 1u);
  return (unsigned short)(u >> 16);
}
// HW packed RNE convert: lo16 = bf16(a), hi16 = bf16(b)
__device__ __forceinline__ unsigned cvt_pk_bf16(float a, float b) {
  unsigned r;
  asm("v_cvt_pk_bf16_f32 %0, %1, %2" : "=v"(r) : "v"(a), "v"(b));
  return r;
}
__device__ __forceinline__ float bf_to_f(unsigned us) {
  return __uint_as_float(us << 16);
}

// ---- in-LDS bitonic sort, ascending, N power of two ----
template <int N>
__device__ void bitonic_sort(unsigned long long* buf) {
  for (int k = 2; k <= N; k <<= 1) {
    for (int j = k >> 1; j > 0; j >>= 1) {
      for (int e = threadIdx.x; e < N; e += blockDim.x) {
        int p = e ^ j;
        if (p > e) {
          unsigned long long a = buf[e], b = buf[p];
          bool up = ((e & k) == 0);
          if (up ? (a > b) : (a < b)) { buf[e] = b; buf[p] = a; }
        }
      }
      __syncthreads();
    }
  }
}

// =================== P0: Q fp32 -> bf16 + per-query norms ===================
__global__ void p0_qprep(const float* __restrict__ Q, unsigned short* __restrict__ Qp,
                         float* __restrict__ norms) {
  const int q = blockIdx.x, d = threadIdx.x;  // 128 threads
  float v = Q[q * DQ + d];
  Qp[q * DQ + d] = f2bf(v);
  float ss = v * v;
#pragma unroll
  for (int m = 1; m < 64; m <<= 1) ss += __shfl_xor(ss, m);
  __shared__ float part[2];
  if ((d & 63) == 0) part[d >> 6] = ss;
  __syncthreads();
  if (d == 0) norms[q] = sqrtf(part[0] + part[1]);
}

// =================== K1: pipelined bf16 MFMA filter ===================
// 256 thr = 4 waves. Tile: 256 q x 64 items, full K=128 staged in LDS (bf16).
// Wave w covers queries [w*64, w*64+64), all 64 items. A = items, B = queries:
// C row = item, col = query -> chunk max = 3 reg-fmax + shfl_xor(16,32).
// M is CHUNK-MAJOR [NCHP][256]: each block flushes 16 KB contiguous (coalesced).
// launch_bounds(256,2): VGPR cap 256 — the r3/r4 (256,4)=128-reg cap spilled the
// st[8] prefetch regs to scratch (WRITE_SIZE 806 MB vs 32 MB of real stores).
__device__ __forceinline__ unsigned xs_off(int x, int d) {
  unsigned byte = (unsigned)(x * 256 + d * 2);
  unsigned slot = (unsigned)((((x >> 2) & 3) << 1) | (x & 1));
  return byte ^ (slot << 4);
}

__global__ __launch_bounds__(256, 2) void k1_filter(
    const unsigned short* __restrict__ Qp, const float* __restrict__ It,
    unsigned short* __restrict__ M) {
  __shared__ unsigned Xs32[4096];                        // 16 KB: [64 x][128 d] bf16 swizzled
  __shared__ __align__(16) unsigned short Ms[32][256];   // 16 KB: [chunk-local][query]
  const int t = threadIdx.x;
  const int xg = (t & 15) * 4;          // item quad within tile
  const int dbase = (t >> 4) * 8;       // 8 consecutive d rows per thread
  const int l = t & 63, w = t >> 6;
  const int wq = w * 64;                // wave's query base
  const int lm = l & 15, h = l >> 4;
  const int tile0 = blockIdx.x * TPB;

  float4 st[8];
  {  // prologue: issue loads for tile0
    int x0 = tile0 * TI;
    bool ok = (x0 < XT);
#pragma unroll
    for (int r = 0; r < 8; ++r)
      st[r] = ok ? *(const float4*)&It[(size_t)(dbase + r) * XT + x0 + xg]
                 : make_float4(0.f, 0.f, 0.f, 0.f);
  }

  for (int tt = 0; tt < TPB; ++tt) {
    // ---- convert staged regs -> Xs (bf16, swizzled) ----
#pragma unroll
    for (int rp = 0; rp < 4; ++rp) {
      int d0 = dbase + rp * 2;
      float a0[4] = {st[rp * 2].x, st[rp * 2].y, st[rp * 2].z, st[rp * 2].w};
      float a1[4] = {st[rp * 2 + 1].x, st[rp * 2 + 1].y, st[rp * 2 + 1].z, st[rp * 2 + 1].w};
#pragma unroll
      for (int j = 0; j < 4; ++j)
        Xs32[xs_off(xg + j, d0) >> 2] = cvt_pk_bf16(a0[j], a1[j]);
    }
    // ---- issue loads for next tile (overlaps with MFMA below) ----
    if (tt + 1 < TPB) {
      int x0 = (tile0 + tt + 1) * TI;
      bool ok = (x0 < XT);
#pragma unroll
      for (int r = 0; r < 8; ++r)
        st[r] = ok ? *(const float4*)&It[(size_t)(dbase + r) * XT + x0 + xg]
                   : make_float4(0.f, 0.f, 0.f, 0.f);
    }
    __syncthreads();

    // ---- MFMA: A = items (LDS), B = queries (global, L2-hot) ----
    f32x4 acc[4][4];
#pragma unroll
    for (int a = 0; a < 4; ++a)
#pragma unroll
      for (int b = 0; b < 4; ++b) acc[a][b] = (f32x4){0.f, 0.f, 0.f, 0.f};

#pragma unroll
    for (int n = 0; n < 4; ++n) {
      bf16x8 afr[4];
#pragma unroll
      for (int a = 0; a < 4; ++a)
        afr[a] = *(const bf16x8*)((const char*)Xs32 + xs_off(a * 16 + lm, n * 32 + h * 8));
#pragma unroll
      for (int b = 0; b < 4; ++b) {
        bf16x8 bfr = *(const bf16x8*)&Qp[(size_t)(wq + b * 16 + lm) * DQ + n * 32 + h * 8];
#pragma unroll
        for (int a = 0; a < 4; ++a)
          acc[a][b] = __builtin_amdgcn_mfma_f32_16x16x32_bf16(afr[a], bfr, acc[a][b], 0, 0, 0);
      }
    }

    // ---- epilogue: per-(chunk a, query col) max into chunk-major Ms ----
#pragma unroll
    for (int a = 0; a < 4; ++a)
#pragma unroll
      for (int b = 0; b < 4; ++b) {
        f32x4 v = acc[a][b];
        float m0 = fmaxf(fmaxf(v.x, v.y), fmaxf(v.z, v.w));
        m0 = fmaxf(m0, __shfl_xor(m0, 16));
        m0 = fmaxf(m0, __shfl_xor(m0, 32));
        if (l < 16)
          Ms[(tt & 7) * 4 + a][wq + b * 16 + lm] =
              (unsigned short)(cvt_pk_bf16(m0, 0.f) & 0xffffu);
      }
    __syncthreads();

    // ---- flush 32 chunk rows (16 KB contiguous, fully coalesced) every 8 tiles ----
    if ((tt & 7) == 7) {
      const uint4* srcv = (const uint4*)&Ms[0][0];
      uint4* dstv = (uint4*)(M + ((size_t)tile0 * 4 + (size_t)(tt >> 3) * 32) * 256);
#pragma unroll
      for (int i = 0; i < 4; ++i) dstv[t + i * 256] = srcv[t + i * 256];
      // NOTE: no extra sync needed — next Ms writes happen after next tile's
      // mid-loop __syncthreads(), which orders them after this flush.
    }
  }
}

// =================== K2a: per-query histogram of chunk maxima (chunk-major reads) ===================
__global__ __launch_bounds__(256) void k2a_hist(
    const unsigned short* __restrict__ M, const float* __restrict__ norms,
    int* __restrict__ ghist) {
  const int t = threadIdx.x;
  __shared__ float s_invn[BQ];
  s_invn[t] = 1.0f / norms[t];
  __syncthreads();
  const uint4* src = (const uint4*)(M + (size_t)blockIdx.x * 64 * 256);
  for (int i = t; i < 2048; i += 256) {  // 64 chunk rows x 32 uint4
    uint4 v = src[i];
    const int q0 = (i & 31) * 8;
    unsigned uu[4] = {v.x, v.y, v.z, v.w};
#pragma unroll
    for (int m = 0; m < 4; ++m) {
#pragma unroll
      for (int s = 0; s < 2; ++s) {
        float val = bf_to_f(s ? (uu[m] >> 16) : (uu[m] & 0xffffu));
        int q = q0 + m * 2 + s;
        float z = val * s_invn[q];
        if (z >= ZLO) {
          int bin = (int)((z - ZLO) * (1.0f / BINW));
          if (bin > BINS - 1) bin = BINS - 1;
          atomicAdd(&ghist[q * BINS + bin], 1);
        }
      }
    }
  }
}

// =================== K2b: per-query threshold from histogram suffix-scan ===================
__global__ __launch_bounds__(512) void k2b_thr(
    const int* __restrict__ ghist, const float* __restrict__ norms,
    float* __restrict__ thrArr, int* __restrict__ cnt) {
  const int q = blockIdx.x, b = threadIdx.x;  // 512 threads = BINS
  __shared__ int sfx[BINS];
  sfx[b] = ghist[q * BINS + b];
  __syncthreads();
  for (int off = 1; off < BINS; off <<= 1) {  // suffix sum
    int v = (b + off < BINS) ? sfx[b + off] : 0;
    __syncthreads();
    sfx[b] += v;
    __syncthreads();
  }
  bool p = sfx[b] >= KTOP;
  bool pn = (b < BINS - 1) ? (sfx[b + 1] >= KTOP) : false;
  if (b == 0) {
    cnt[q] = 0;
    if (sfx[0] < KTOP) thrArr[q] = -3.0e38f;  // unreachable for this data; safety
  }
  if (p && !pn)  // unique boundary: b = largest bin with suffix >= KTOP
    thrArr[q] = (ZLO + (float)(b - 1) * BINW) * norms[q] - DELTA;
}

// =================== K2c: emit candidate chunks (chunk-major reads, sparse atomics) ===================
__global__ __launch_bounds__(256) void k2c_emit(
    const unsigned short* __restrict__ M, const float* __restrict__ thrArr,
    int* __restrict__ list, int* __restrict__ cnt) {
  const int t = threadIdx.x;
  __shared__ float s_thr[BQ];
  s_thr[t] = thrArr[t];
  __syncthreads();
  const int c0 = blockIdx.x * 64;
  const uint4* src = (const uint4*)(M + (size_t)c0 * 256);
  for (int i = t; i < 2048; i += 256) {
    uint4 v = src[i];
    const int q0 = (i & 31) * 8;
    const int c = c0 + (i >> 5);
    unsigned uu[4] = {v.x, v.y, v.z, v.w};
#pragma unroll
    for (int m = 0; m < 4; ++m) {
#pragma unroll
      for (int s = 0; s < 2; ++s) {
        float val = bf_to_f(s ? (uu[m] >> 16) : (uu[m] & 0xffffu));
        int q = q0 + m * 2 + s;
        if (val >= s_thr[q]) {
          int pos = atomicAdd(&cnt[q], 1);
          if (pos < CAP) list[q * CAP + pos] = c;
        }
      }
    }
  }
}

// =================== K3: EXACT fp32 rescore of listed chunks (unchanged math) ===================
__global__ __launch_bounds__(256) void k3_rescore(
    const float* __restrict__ Q, const float* __restrict__ It,
    const int* __restrict__ list, const int* __restrict__ cnt_in,
    unsigned long long* __restrict__ cand) {
  const int q = blockIdx.x >> 4;
  const int sg = blockIdx.x & 15;
  __shared__ float qv[DQ];
  if (threadIdx.x < DQ) qv[threadIdx.x] = Q[q * DQ + threadIdx.x];
  __syncthreads();
  const int s = threadIdx.x >> 4;
  const int it = threadIdx.x & 15;
  const int gs = sg * 16 + s;
  int n = cnt_in[q];
  if (n > CAP) n = CAP;
  unsigned long long out = 0ULL;
  if (gs < n) {
    const int chunk = list[q * CAP + gs];
    const int x = chunk * CHUNK + it;
    float a = 0.f;
#pragma unroll 8
    for (int d = 0; d < DQ; ++d) a = fmaf(qv[d], It[(size_t)d * XT + x], a);
    out = packkv(a, (unsigned)x);
  }
  cand[(size_t)q * NCAND + gs * CHUNK + it] = out;
}

// =================== K4: final per-query top-100 ===================
__global__ __launch_bounds__(512) void k4_final(
    const unsigned long long* __restrict__ cand, float* __restrict__ out) {
  const int q = blockIdx.x;
  __shared__ unsigned long long buf[NCAND];
  for (int s = threadIdx.x; s < NCAND; s += blockDim.x) buf[s] = cand[(size_t)q * NCAND + s];
  __syncthreads();
  bitonic_sort<NCAND>(buf);
  for (int r = threadIdx.x; r < KTOP; r += blockDim.x) {
    unsigned long long e = buf[NCAND - 1 - r];
    out[q * KTOP + r] = pk_val(e);                       // topk_logits
    out[BQ * KTOP + q * KTOP + r] = (float)pk_id(e);     // topk_item_ids
  }
}

extern "C" void kernel_launch(void* const* d_in, const int* in_sizes, int n_in,
                              void* d_out, int out_size, void* d_ws, size_t ws_size,
                              hipStream_t stream) {
  const float* Q = (const float*)d_in[0];   // [256,128]
  const float* It = (const float*)d_in[1];  // [128,1000000]
  float* out = (float*)d_out;               // [25600 logits][25600 ids]
  char* ws = (char*)d_ws;
  // ws layout (bytes):
  //   M      : 0          .. 32,014,336   (62528 x 256 bf16, CHUNK-MAJOR)
  //   ghist  : 32,014,336 .. +524,288     (256 x 512 int)
  //   thrArr : 32,538,624 .. +1,024
  //   list   : 32,539,648 .. +262,144
  //   cnt    : 32,801,792 .. +1,024
  //   norms  : 32,802,816 .. +1,024
  //   Qp     : 32,803,840 .. +65,536
  //   cand   : 33,554,432 .. +8,388,608
  unsigned short* M = (unsigned short*)ws;
  int* ghist = (int*)(ws + 32014336);
  float* thrArr = (float*)(ws + 32538624);
  int* list = (int*)(ws + 32539648);
  int* cnt = (int*)(ws + 32801792);
  float* norms = (float*)(ws + 32802816);
  unsigned short* Qp = (unsigned short*)(ws + 32803840);
  unsigned long long* cand = (unsigned long long*)(ws + 33554432);

  hipMemsetAsync(ghist, 0, BQ * BINS * sizeof(int), stream);
  p0_qprep<<<dim3(BQ), dim3(DQ), 0, stream>>>(Q, Qp, norms);
  k1_filter<<<dim3(NBLK), dim3(256), 0, stream>>>(Qp, It, M);
  k2a_hist<<<dim3(NBLK), dim3(256), 0, stream>>>(M, norms, ghist);
  k2b_thr<<<dim3(BQ), dim3(512), 0, stream>>>(ghist, norms, thrArr, cnt);
  k2c_emit<<<dim3(NBLK), dim3(256), 0, stream>>>(M, thrArr, list, cnt);
  k3_rescore<<<dim3(BQ * 16), dim3(256), 0, stream>>>(Q, It, list, cnt, cand);
  k4_final<<<dim3(BQ), dim3(512), 0, stream>>>(cand, out);
}

// Round 6
// 365.317 us; speedup vs baseline: 2.2832x; 1.2857x over previous
//
#include <hip/hip_runtime.h>
#include <hip/hip_bf16.h>
#include <math.h>

// Problem constants (fixed by the reference setup)
#define XT      1000000   // items
#define DQ      128       // dims
#define BQ      256       // queries
#define TI      64        // items per K1 tile (XT = 64 * 15625 exactly)
#define NTILES  15625
#define TPB     16        // tiles per block
#define NBLK    977       // ceil(NTILES/TPB); 977*64 chunks = 62528 rows
#define CHUNK   16        // items per max-chunk
#define NCH     62500     // XT / CHUNK
#define NCHP    62528     // padded chunk rows (NBLK * 64)
#define CAP     256       // max chunks rescored per query
#define NCAND   (CAP * CHUNK)  // 4096
#define KTOP    100
#define DELTA   0.5f      // covers bf16 filter error with margin (validated r1-r5)
#define ZLO     3.0f      // histogram band lower edge (in units of ||q||)
#define BINS    512
#define BINW    0.005f

typedef float f32x4 __attribute__((ext_vector_type(4)));
typedef short bf16x8 __attribute__((ext_vector_type(8)));

// ---- order-preserving float<->uint packing: (score desc, id asc) as one u64 ----
__device__ __forceinline__ unsigned ordf(float f) {
  unsigned u = __float_as_uint(f);
  return (u & 0x80000000u) ? ~u : (u ^ 0x80000000u);
}
__device__ __forceinline__ float unordf(unsigned k) {
  unsigned bits = (k & 0x80000000u) ? (k ^ 0x80000000u) : ~k;
  return __uint_as_float(bits);
}
__device__ __forceinline__ unsigned long long packkv(float v, unsigned id) {
  return ((unsigned long long)ordf(v) << 32) | (unsigned long long)(~id);
}
__device__ __forceinline__ float pk_val(unsigned long long e) { return unordf((unsigned)(e >> 32)); }
__device__ __forceinline__ unsigned pk_id(unsigned long long e) { return ~(unsigned)(e & 0xFFFFFFFFu); }

__device__ __forceinline__ unsigned short f2bf(float f) {  // RNE fp32->bf16
  unsigned u = __float_as_uint(f);
  u += 0x7FFFu + ((u >> 16) & 1u);
  return (unsigned short)(u >> 16);
}
// HW packed RNE convert: lo16 = bf16(a), hi16 = bf16(b)
__device__ __forceinline__ unsigned cvt_pk_bf16(float a, float b) {
  unsigned r;
  asm("v_cvt_pk_bf16_f32 %0, %1, %2" : "=v"(r) : "v"(a), "v"(b));
  return r;
}
__device__ __forceinline__ float bf_to_f(unsigned us) {
  return __uint_as_float(us << 16);
}

// ---- in-LDS bitonic sort, ascending, N power of two ----
template <int N>
__device__ void bitonic_sort(unsigned long long* buf) {
  for (int k = 2; k <= N; k <<= 1) {
    for (int j = k >> 1; j > 0; j >>= 1) {
      for (int e = threadIdx.x; e < N; e += blockDim.x) {
        int p = e ^ j;
        if (p > e) {
          unsigned long long a = buf[e], b = buf[p];
          bool up = ((e & k) == 0);
          if (up ? (a > b) : (a < b)) { buf[e] = b; buf[p] = a; }
        }
      }
      __syncthreads();
    }
  }
}

// =================== P0: Q fp32 -> bf16 + norms + ghist zero ===================
// Also zeroes ghist (256x512 ints) so no hipMemsetAsync node sits in the graph
// (r5 profile showed the 512 KB fillBuffer blit at 322 us in the dispatch stream).
__global__ void p0_qprep(const float* __restrict__ Q, unsigned short* __restrict__ Qp,
                         float* __restrict__ norms, uint4* __restrict__ ghist4) {
  const int q = blockIdx.x, d = threadIdx.x;  // 256 blocks x 128 threads
  ghist4[q * DQ + d] = make_uint4(0, 0, 0, 0);  // 32768 threads x 16 B = 512 KB
  float v = Q[q * DQ + d];
  Qp[q * DQ + d] = f2bf(v);
  float ss = v * v;
#pragma unroll
  for (int m = 1; m < 64; m <<= 1) ss += __shfl_xor(ss, m);
  __shared__ float part[2];
  if ((d & 63) == 0) part[d >> 6] = ss;
  __syncthreads();
  if (d == 0) norms[q] = sqrtf(part[0] + part[1]);
}

// =================== K1: pipelined bf16 MFMA filter ===================
// 256 thr = 4 waves. Tile: 256 q x 64 items, full K=128 staged in LDS (bf16).
// Wave w covers queries [w*64, w*64+64), all 64 items. A = items, B = queries:
// C row = item, col = query -> chunk max = 3 reg-fmax + shfl_xor(16,32).
// Q-fragments are tile-invariant -> hoisted to 64 VGPR before the tile loop.
// M is CHUNK-MAJOR [NCHP][256]: each block flushes 16 KB contiguous (coalesced).
// launch_bounds(256,2): VGPR cap 256 (the (256,4)=128 cap spilled st[] to scratch).
__device__ __forceinline__ unsigned xs_off(int x, int d) {
  unsigned byte = (unsigned)(x * 256 + d * 2);
  unsigned slot = (unsigned)((((x >> 2) & 3) << 1) | (x & 1));
  return byte ^ (slot << 4);
}

__global__ __launch_bounds__(256, 2) void k1_filter(
    const unsigned short* __restrict__ Qp, const float* __restrict__ It,
    unsigned short* __restrict__ M) {
  __shared__ unsigned Xs32[4096];                        // 16 KB: [64 x][128 d] bf16 swizzled
  __shared__ __align__(16) unsigned short Ms[32][256];   // 16 KB: [chunk-local][query]
  const int t = threadIdx.x;
  const int xg = (t & 15) * 4;          // item quad within tile
  const int dbase = (t >> 4) * 8;       // 8 consecutive d rows per thread
  const int l = t & 63, w = t >> 6;
  const int wq = w * 64;                // wave's query base
  const int lm = l & 15, h = l >> 4;
  const int tile0 = blockIdx.x * TPB;

  // ---- hoist the wave's 16 Q-fragments (tile-invariant) into registers ----
  bf16x8 qfr[4][4];  // [k-step n][query sub-tile b]
#pragma unroll
  for (int n = 0; n < 4; ++n)
#pragma unroll
    for (int b = 0; b < 4; ++b)
      qfr[n][b] = *(const bf16x8*)&Qp[(size_t)(wq + b * 16 + lm) * DQ + n * 32 + h * 8];

  float4 st[8];
  {  // prologue: issue loads for tile0
    int x0 = tile0 * TI;
    bool ok = (x0 < XT);
#pragma unroll
    for (int r = 0; r < 8; ++r)
      st[r] = ok ? *(const float4*)&It[(size_t)(dbase + r) * XT + x0 + xg]
                 : make_float4(0.f, 0.f, 0.f, 0.f);
  }

  for (int tt = 0; tt < TPB; ++tt) {
    // ---- convert staged regs -> Xs (bf16, swizzled), 4x ds_write_b128 ----
    // For fixed item x, the 4 cvt_pk results (d-pairs) are contiguous 16 B at
    // x*256 + dbase*2; the XOR swizzle flips only byte bits 4-6 -> stays aligned.
#pragma unroll
    for (int j = 0; j < 4; ++j) {
      unsigned wv0 = cvt_pk_bf16(((const float*)&st[0])[j], ((const float*)&st[1])[j]);
      unsigned wv1 = cvt_pk_bf16(((const float*)&st[2])[j], ((const float*)&st[3])[j]);
      unsigned wv2 = cvt_pk_bf16(((const float*)&st[4])[j], ((const float*)&st[5])[j]);
      unsigned wv3 = cvt_pk_bf16(((const float*)&st[6])[j], ((const float*)&st[7])[j]);
      *(uint4*)((char*)Xs32 + xs_off(xg + j, dbase)) = make_uint4(wv0, wv1, wv2, wv3);
    }
    // ---- issue loads for next tile (overlaps with MFMA below) ----
    if (tt + 1 < TPB) {
      int x0 = (tile0 + tt + 1) * TI;
      bool ok = (x0 < XT);
#pragma unroll
      for (int r = 0; r < 8; ++r)
        st[r] = ok ? *(const float4*)&It[(size_t)(dbase + r) * XT + x0 + xg]
                   : make_float4(0.f, 0.f, 0.f, 0.f);
    }
    __syncthreads();

    // ---- MFMA: A = items (LDS), B = queries (registers) ----
    f32x4 acc[4][4];
#pragma unroll
    for (int a = 0; a < 4; ++a)
#pragma unroll
      for (int b = 0; b < 4; ++b) acc[a][b] = (f32x4){0.f, 0.f, 0.f, 0.f};

#pragma unroll
    for (int n = 0; n < 4; ++n) {
      bf16x8 afr[4];
#pragma unroll
      for (int a = 0; a < 4; ++a)
        afr[a] = *(const bf16x8*)((const char*)Xs32 + xs_off(a * 16 + lm, n * 32 + h * 8));
#pragma unroll
      for (int b = 0; b < 4; ++b)
#pragma unroll
        for (int a = 0; a < 4; ++a)
          acc[a][b] = __builtin_amdgcn_mfma_f32_16x16x32_bf16(afr[a], qfr[n][b], acc[a][b], 0, 0, 0);
    }

    // ---- epilogue: per-(chunk a, query col) max into chunk-major Ms ----
#pragma unroll
    for (int a = 0; a < 4; ++a)
#pragma unroll
      for (int b = 0; b < 4; ++b) {
        f32x4 v = acc[a][b];
        float m0 = fmaxf(fmaxf(v.x, v.y), fmaxf(v.z, v.w));
        m0 = fmaxf(m0, __shfl_xor(m0, 16));
        m0 = fmaxf(m0, __shfl_xor(m0, 32));
        if (l < 16)
          Ms[(tt & 7) * 4 + a][wq + b * 16 + lm] =
              (unsigned short)(cvt_pk_bf16(m0, 0.f) & 0xffffu);
      }
    __syncthreads();

    // ---- flush 32 chunk rows (16 KB contiguous, fully coalesced) every 8 tiles ----
    if ((tt & 7) == 7) {
      const uint4* srcv = (const uint4*)&Ms[0][0];
      uint4* dstv = (uint4*)(M + ((size_t)tile0 * 4 + (size_t)(tt >> 3) * 32) * 256);
#pragma unroll
      for (int i = 0; i < 4; ++i) dstv[t + i * 256] = srcv[t + i * 256];
      // NOTE: no extra sync needed — next Ms writes happen after next tile's
      // mid-loop __syncthreads(), which orders them after this flush.
    }
  }
}

// =================== K2a: per-query histogram of chunk maxima (chunk-major reads) ===================
__global__ __launch_bounds__(256) void k2a_hist(
    const unsigned short* __restrict__ M, const float* __restrict__ norms,
    int* __restrict__ ghist) {
  const int t = threadIdx.x;
  __shared__ float s_invn[BQ];
  s_invn[t] = 1.0f / norms[t];
  __syncthreads();
  const uint4* src = (const uint4*)(M + (size_t)blockIdx.x * 64 * 256);
  for (int i = t; i < 2048; i += 256) {  // 64 chunk rows x 32 uint4
    uint4 v = src[i];
    const int q0 = (i & 31) * 8;
    unsigned uu[4] = {v.x, v.y, v.z, v.w};
#pragma unroll
    for (int m = 0; m < 4; ++m) {
#pragma unroll
      for (int s = 0; s < 2; ++s) {
        float val = bf_to_f(s ? (uu[m] >> 16) : (uu[m] & 0xffffu));
        int q = q0 + m * 2 + s;
        float z = val * s_invn[q];
        if (z >= ZLO) {
          int bin = (int)((z - ZLO) * (1.0f / BINW));
          if (bin > BINS - 1) bin = BINS - 1;
          atomicAdd(&ghist[q * BINS + bin], 1);
        }
      }
    }
  }
}

// =================== K2b: per-query threshold from histogram suffix-scan ===================
__global__ __launch_bounds__(512) void k2b_thr(
    const int* __restrict__ ghist, const float* __restrict__ norms,
    float* __restrict__ thrArr, int* __restrict__ cnt) {
  const int q = blockIdx.x, b = threadIdx.x;  // 512 threads = BINS
  __shared__ int sfx[BINS];
  sfx[b] = ghist[q * BINS + b];
  __syncthreads();
  for (int off = 1; off < BINS; off <<= 1) {  // suffix sum
    int v = (b + off < BINS) ? sfx[b + off] : 0;
    __syncthreads();
    sfx[b] += v;
    __syncthreads();
  }
  bool p = sfx[b] >= KTOP;
  bool pn = (b < BINS - 1) ? (sfx[b + 1] >= KTOP) : false;
  if (b == 0) {
    cnt[q] = 0;
    if (sfx[0] < KTOP) thrArr[q] = -3.0e38f;  // unreachable for this data; safety
  }
  if (p && !pn)  // unique boundary: b = largest bin with suffix >= KTOP
    thrArr[q] = (ZLO + (float)(b - 1) * BINW) * norms[q] - DELTA;
}

// =================== K2c: emit candidate chunks (chunk-major reads, sparse atomics) ===================
__global__ __launch_bounds__(256) void k2c_emit(
    const unsigned short* __restrict__ M, const float* __restrict__ thrArr,
    int* __restrict__ list, int* __restrict__ cnt) {
  const int t = threadIdx.x;
  __shared__ float s_thr[BQ];
  s_thr[t] = thrArr[t];
  __syncthreads();
  const int c0 = blockIdx.x * 64;
  const uint4* src = (const uint4*)(M + (size_t)c0 * 256);
  for (int i = t; i < 2048; i += 256) {
    uint4 v = src[i];
    const int q0 = (i & 31) * 8;
    const int c = c0 + (i >> 5);
    unsigned uu[4] = {v.x, v.y, v.z, v.w};
#pragma unroll
    for (int m = 0; m < 4; ++m) {
#pragma unroll
      for (int s = 0; s < 2; ++s) {
        float val = bf_to_f(s ? (uu[m] >> 16) : (uu[m] & 0xffffu));
        int q = q0 + m * 2 + s;
        if (val >= s_thr[q]) {
          int pos = atomicAdd(&cnt[q], 1);
          if (pos < CAP) list[q * CAP + pos] = c;
        }
      }
    }
  }
}

// =================== K3: EXACT fp32 rescore of listed chunks (unchanged math) ===================
__global__ __launch_bounds__(256) void k3_rescore(
    const float* __restrict__ Q, const float* __restrict__ It,
    const int* __restrict__ list, const int* __restrict__ cnt_in,
    unsigned long long* __restrict__ cand) {
  const int q = blockIdx.x >> 4;
  const int sg = blockIdx.x & 15;
  __shared__ float qv[DQ];
  if (threadIdx.x < DQ) qv[threadIdx.x] = Q[q * DQ + threadIdx.x];
  __syncthreads();
  const int s = threadIdx.x >> 4;
  const int it = threadIdx.x & 15;
  const int gs = sg * 16 + s;
  int n = cnt_in[q];
  if (n > CAP) n = CAP;
  unsigned long long out = 0ULL;
  if (gs < n) {
    const int chunk = list[q * CAP + gs];
    const int x = chunk * CHUNK + it;
    float a = 0.f;
#pragma unroll 8
    for (int d = 0; d < DQ; ++d) a = fmaf(qv[d], It[(size_t)d * XT + x], a);
    out = packkv(a, (unsigned)x);
  }
  cand[(size_t)q * NCAND + gs * CHUNK + it] = out;
}

// =================== K4: final per-query top-100 ===================
__global__ __launch_bounds__(512) void k4_final(
    const unsigned long long* __restrict__ cand, float* __restrict__ out) {
  const int q = blockIdx.x;
  __shared__ unsigned long long buf[NCAND];
  for (int s = threadIdx.x; s < NCAND; s += blockDim.x) buf[s] = cand[(size_t)q * NCAND + s];
  __syncthreads();
  bitonic_sort<NCAND>(buf);
  for (int r = threadIdx.x; r < KTOP; r += blockDim.x) {
    unsigned long long e = buf[NCAND - 1 - r];
    out[q * KTOP + r] = pk_val(e);                       // topk_logits
    out[BQ * KTOP + q * KTOP + r] = (float)pk_id(e);     // topk_item_ids
  }
}

extern "C" void kernel_launch(void* const* d_in, const int* in_sizes, int n_in,
                              void* d_out, int out_size, void* d_ws, size_t ws_size,
                              hipStream_t stream) {
  const float* Q = (const float*)d_in[0];   // [256,128]
  const float* It = (const float*)d_in[1];  // [128,1000000]
  float* out = (float*)d_out;               // [25600 logits][25600 ids]
  char* ws = (char*)d_ws;
  // ws layout (bytes):
  //   M      : 0          .. 32,014,336   (62528 x 256 bf16, CHUNK-MAJOR)
  //   ghist  : 32,014,336 .. +524,288     (256 x 512 int)
  //   thrArr : 32,538,624 .. +1,024
  //   list   : 32,539,648 .. +262,144
  //   cnt    : 32,801,792 .. +1,024
  //   norms  : 32,802,816 .. +1,024
  //   Qp     : 32,803,840 .. +65,536
  //   cand   : 33,554,432 .. +8,388,608
  unsigned short* M = (unsigned short*)ws;
  int* ghist = (int*)(ws + 32014336);
  float* thrArr = (float*)(ws + 32538624);
  int* list = (int*)(ws + 32539648);
  int* cnt = (int*)(ws + 32801792);
  float* norms = (float*)(ws + 32802816);
  unsigned short* Qp = (unsigned short*)(ws + 32803840);
  unsigned long long* cand = (unsigned long long*)(ws + 33554432);

  p0_qprep<<<dim3(BQ), dim3(DQ), 0, stream>>>(Q, Qp, norms, (uint4*)ghist);
  k1_filter<<<dim3(NBLK), dim3(256), 0, stream>>>(Qp, It, M);
  k2a_hist<<<dim3(NBLK), dim3(256), 0, stream>>>(M, norms, ghist);
  k2b_thr<<<dim3(BQ), dim3(512), 0, stream>>>(ghist, norms, thrArr, cnt);
  k2c_emit<<<dim3(NBLK), dim3(256), 0, stream>>>(M, thrArr, list, cnt);
  k3_rescore<<<dim3(BQ * 16), dim3(256), 0, stream>>>(Q, It, list, cnt, cand);
  k4_final<<<dim3(BQ), dim3(512), 0, stream>>>(cand, out);
}

// Round 7
// 286.864 us; speedup vs baseline: 2.9077x; 1.2735x over previous
//
#include <hip/hip_runtime.h>
#include <hip/hip_bf16.h>
#include <math.h>

// Problem constants (fixed by the reference setup)
#define XT      1000000   // items
#define DQ      128       // dims
#define BQ      256       // queries
#define TI      64        // items per K1 tile (XT = 64 * 15625 exactly)
#define NTILES  15625
#define TPB     16        // tiles per block
#define NBLK    977       // ceil(NTILES/TPB); 977*64 chunks = 62528 rows
#define CHUNK   16        // items per max-chunk
#define NCH     62500     // XT / CHUNK
#define NCHP    62528     // padded chunk rows (NBLK * 64)
#define CAP     256       // max chunks rescored per query
#define NCAND   (CAP * CHUNK)  // 4096
#define KTOP    100
#define DELTA   0.5f      // covers bf16 filter error with margin (validated r1-r6)
#define ZLO     3.0f      // histogram band lower edge (in units of ||q||)
#define BINS    512
#define BINW    0.005f
#define K4BINS  1024
#define K4SEL   512

typedef float f32x4 __attribute__((ext_vector_type(4)));
typedef short bf16x8 __attribute__((ext_vector_type(8)));

// ---- order-preserving float<->uint packing: (score desc, id asc) as one u64 ----
__device__ __forceinline__ unsigned ordf(float f) {
  unsigned u = __float_as_uint(f);
  return (u & 0x80000000u) ? ~u : (u ^ 0x80000000u);
}
__device__ __forceinline__ float unordf(unsigned k) {
  unsigned bits = (k & 0x80000000u) ? (k ^ 0x80000000u) : ~k;
  return __uint_as_float(bits);
}
__device__ __forceinline__ unsigned long long packkv(float v, unsigned id) {
  return ((unsigned long long)ordf(v) << 32) | (unsigned long long)(~id);
}
__device__ __forceinline__ float pk_val(unsigned long long e) { return unordf((unsigned)(e >> 32)); }
__device__ __forceinline__ unsigned pk_id(unsigned long long e) { return ~(unsigned)(e & 0xFFFFFFFFu); }

__device__ __forceinline__ unsigned short f2bf(float f) {  // RNE fp32->bf16
  unsigned u = __float_as_uint(f);
  u += 0x7FFFu + ((u >> 16) & 1u);
  return (unsigned short)(u >> 16);
}
// HW packed RNE convert: lo16 = bf16(a), hi16 = bf16(b)
__device__ __forceinline__ unsigned cvt_pk_bf16(float a, float b) {
  unsigned r;
  asm("v_cvt_pk_bf16_f32 %0, %1, %2" : "=v"(r) : "v"(a), "v"(b));
  return r;
}
__device__ __forceinline__ float bf_to_f(unsigned us) {
  return __uint_as_float(us << 16);
}

// ---- in-LDS bitonic sort, ascending, N power of two ----
template <int N>
__device__ void bitonic_sort(unsigned long long* buf) {
  for (int k = 2; k <= N; k <<= 1) {
    for (int j = k >> 1; j > 0; j >>= 1) {
      for (int e = threadIdx.x; e < N; e += blockDim.x) {
        int p = e ^ j;
        if (p > e) {
          unsigned long long a = buf[e], b = buf[p];
          bool up = ((e & k) == 0);
          if (up ? (a > b) : (a < b)) { buf[e] = b; buf[p] = a; }
        }
      }
      __syncthreads();
    }
  }
}

// =================== P0: Q fp32 -> bf16 + norms + ghist zero ===================
__global__ void p0_qprep(const float* __restrict__ Q, unsigned short* __restrict__ Qp,
                         float* __restrict__ norms, uint4* __restrict__ ghist4) {
  const int q = blockIdx.x, d = threadIdx.x;  // 256 blocks x 128 threads
  ghist4[q * DQ + d] = make_uint4(0, 0, 0, 0);  // 32768 threads x 16 B = 512 KB
  float v = Q[q * DQ + d];
  Qp[q * DQ + d] = f2bf(v);
  float ss = v * v;
#pragma unroll
  for (int m = 1; m < 64; m <<= 1) ss += __shfl_xor(ss, m);
  __shared__ float part[2];
  if ((d & 63) == 0) part[d >> 6] = ss;
  __syncthreads();
  if (d == 0) norms[q] = sqrtf(part[0] + part[1]);
}

// =================== K1: pipelined bf16 MFMA filter + fused histogram ===================
// 256 thr = 4 waves. Tile: 256 q x 64 items, full K=128 staged in LDS (bf16, dbuf).
// Wave w covers queries [w*64, w*64+64); A = items, B = queries.
// Double-buffered Xs -> ONE barrier per tile (stage->MFMA), plus one pre-flush
// barrier every 8 tiles. Race audit: stage(tt+1) writes buf[(tt+1)&1], whose last
// reader was MFMA(tt-1); any wave at stage(tt+1) passed barrier(tt), so all waves
// finished MFMA(tt-1). flush(7) vs epilogue(8) ordered by barrier(8).
// Histogram (was K2a) fused into the epilogue: one atomic per chunk-max with
// z >= ZLO (~2% of values) -> saves a full 32 MB M read pass.
__device__ __forceinline__ unsigned xs_off(int x, int d) {
  unsigned byte = (unsigned)(x * 256 + d * 2);
  unsigned slot = (unsigned)((((x >> 2) & 3) << 1) | (x & 1));
  return byte ^ (slot << 4);
}

__global__ __launch_bounds__(256, 2) void k1_filter(
    const unsigned short* __restrict__ Qp, const float* __restrict__ It,
    const float* __restrict__ norms, unsigned short* __restrict__ M,
    int* __restrict__ ghist) {
  __shared__ __align__(16) unsigned Xs32[2][4096];       // 32 KB: 2 x [64 x][128 d] bf16 swz
  __shared__ __align__(16) unsigned short Ms[32][256];   // 16 KB: [chunk-local][query]
  const int t = threadIdx.x;
  const int xg = (t & 15) * 4;          // item quad within tile
  const int dbase = (t >> 4) * 8;       // 8 consecutive d rows per thread
  const int l = t & 63, w = t >> 6;
  const int wq = w * 64;                // wave's query base
  const int lm = l & 15, h = l >> 4;
  const int tile0 = blockIdx.x * TPB;

  // ---- hoist the wave's 16 Q-fragments (tile-invariant) into registers ----
  bf16x8 qfr[4][4];  // [k-step n][query sub-tile b]
#pragma unroll
  for (int n = 0; n < 4; ++n)
#pragma unroll
    for (int b = 0; b < 4; ++b)
      qfr[n][b] = *(const bf16x8*)&Qp[(size_t)(wq + b * 16 + lm) * DQ + n * 32 + h * 8];
  float invq[4];
#pragma unroll
  for (int b = 0; b < 4; ++b) invq[b] = 1.0f / norms[wq + b * 16 + lm];

  float4 st[8];
  {  // prologue: issue loads for tile0
    int x0 = tile0 * TI;
    bool ok = (x0 < XT);
#pragma unroll
    for (int r = 0; r < 8; ++r)
      st[r] = ok ? *(const float4*)&It[(size_t)(dbase + r) * XT + x0 + xg]
                 : make_float4(0.f, 0.f, 0.f, 0.f);
  }

  for (int tt = 0; tt < TPB; ++tt) {
    unsigned* xsb = &Xs32[tt & 1][0];
    // ---- convert staged regs -> Xs[cur] (bf16, swizzled), 4x ds_write_b128 ----
#pragma unroll
    for (int j = 0; j < 4; ++j) {
      unsigned wv0 = cvt_pk_bf16(((const float*)&st[0])[j], ((const float*)&st[1])[j]);
      unsigned wv1 = cvt_pk_bf16(((const float*)&st[2])[j], ((const float*)&st[3])[j]);
      unsigned wv2 = cvt_pk_bf16(((const float*)&st[4])[j], ((const float*)&st[5])[j]);
      unsigned wv3 = cvt_pk_bf16(((const float*)&st[6])[j], ((const float*)&st[7])[j]);
      *(uint4*)((char*)xsb + xs_off(xg + j, dbase)) = make_uint4(wv0, wv1, wv2, wv3);
    }
    // ---- issue loads for next tile (in flight across the barrier, under MFMA) ----
    if (tt + 1 < TPB) {
      int x0 = (tile0 + tt + 1) * TI;
      bool ok = (x0 < XT);
#pragma unroll
      for (int r = 0; r < 8; ++r)
        st[r] = ok ? *(const float4*)&It[(size_t)(dbase + r) * XT + x0 + xg]
                   : make_float4(0.f, 0.f, 0.f, 0.f);
    }
    __syncthreads();

    // ---- MFMA: A = items (LDS cur buffer), B = queries (registers) ----
    f32x4 acc[4][4];
#pragma unroll
    for (int a = 0; a < 4; ++a)
#pragma unroll
      for (int b = 0; b < 4; ++b) acc[a][b] = (f32x4){0.f, 0.f, 0.f, 0.f};

#pragma unroll
    for (int n = 0; n < 4; ++n) {
      bf16x8 afr[4];
#pragma unroll
      for (int a = 0; a < 4; ++a)
        afr[a] = *(const bf16x8*)((const char*)xsb + xs_off(a * 16 + lm, n * 32 + h * 8));
#pragma unroll
      for (int b = 0; b < 4; ++b)
#pragma unroll
        for (int a = 0; a < 4; ++a)
          acc[a][b] = __builtin_amdgcn_mfma_f32_16x16x32_bf16(afr[a], qfr[n][b], acc[a][b], 0, 0, 0);
    }

    // ---- epilogue: per-(chunk a, query col) max -> Ms + fused histogram ----
#pragma unroll
    for (int a = 0; a < 4; ++a)
#pragma unroll
      for (int b = 0; b < 4; ++b) {
        f32x4 v = acc[a][b];
        float m0 = fmaxf(fmaxf(v.x, v.y), fmaxf(v.z, v.w));
        m0 = fmaxf(m0, __shfl_xor(m0, 16));
        m0 = fmaxf(m0, __shfl_xor(m0, 32));
        if (l < 16) {
          Ms[(tt & 7) * 4 + a][wq + b * 16 + lm] =
              (unsigned short)(cvt_pk_bf16(m0, 0.f) & 0xffffu);
          float z = m0 * invq[b];
          if (z >= ZLO) {
            int bin = (int)((z - ZLO) * (1.0f / BINW));
            if (bin > BINS - 1) bin = BINS - 1;
            atomicAdd(&ghist[(wq + b * 16 + lm) * BINS + bin], 1);
          }
        }
      }

    // ---- flush 32 chunk rows (16 KB contiguous, fully coalesced) every 8 tiles ----
    if ((tt & 7) == 7) {
      __syncthreads();  // all epilogue Ms writes visible
      const uint4* srcv = (const uint4*)&Ms[0][0];
      uint4* dstv = (uint4*)(M + ((size_t)tile0 * 4 + (size_t)(tt >> 3) * 32) * 256);
#pragma unroll
      for (int i = 0; i < 4; ++i) dstv[t + i * 256] = srcv[t + i * 256];
      // next epilogue that reuses Ms rows 0-3 is ordered after barrier(tt+1)
    }
  }
}

// =================== K2b: per-query threshold from histogram suffix-scan ===================
__global__ __launch_bounds__(512) void k2b_thr(
    const int* __restrict__ ghist, const float* __restrict__ norms,
    float* __restrict__ thrArr, int* __restrict__ cnt) {
  const int q = blockIdx.x, b = threadIdx.x;  // 512 threads = BINS
  __shared__ int sfx[BINS];
  sfx[b] = ghist[q * BINS + b];
  __syncthreads();
  for (int off = 1; off < BINS; off <<= 1) {  // suffix sum
    int v = (b + off < BINS) ? sfx[b + off] : 0;
    __syncthreads();
    sfx[b] += v;
    __syncthreads();
  }
  bool p = sfx[b] >= KTOP;
  bool pn = (b < BINS - 1) ? (sfx[b + 1] >= KTOP) : false;
  if (b == 0) {
    cnt[q] = 0;
    if (sfx[0] < KTOP) thrArr[q] = -3.0e38f;  // unreachable for this data; safety
  }
  if (p && !pn)  // unique boundary: b = largest bin with suffix >= KTOP
    thrArr[q] = (ZLO + (float)(b - 1) * BINW) * norms[q] - DELTA;
}

// =================== K2c: emit candidate chunks (chunk-major reads, sparse atomics) ===================
__global__ __launch_bounds__(256) void k2c_emit(
    const unsigned short* __restrict__ M, const float* __restrict__ thrArr,
    int* __restrict__ list, int* __restrict__ cnt) {
  const int t = threadIdx.x;
  __shared__ float s_thr[BQ];
  s_thr[t] = thrArr[t];
  __syncthreads();
  const int c0 = blockIdx.x * 64;
  const uint4* src = (const uint4*)(M + (size_t)c0 * 256);
  for (int i = t; i < 2048; i += 256) {
    uint4 v = src[i];
    const int q0 = (i & 31) * 8;
    const int c = c0 + (i >> 5);
    unsigned uu[4] = {v.x, v.y, v.z, v.w};
#pragma unroll
    for (int m = 0; m < 4; ++m) {
#pragma unroll
      for (int s = 0; s < 2; ++s) {
        float val = bf_to_f(s ? (uu[m] >> 16) : (uu[m] & 0xffffu));
        int q = q0 + m * 2 + s;
        if (val >= s_thr[q]) {
          int pos = atomicAdd(&cnt[q], 1);
          if (pos < CAP) list[q * CAP + pos] = c;
        }
      }
    }
  }
}

// =================== K3: EXACT fp32 rescore of listed chunks (unchanged math) ===================
__global__ __launch_bounds__(256) void k3_rescore(
    const float* __restrict__ Q, const float* __restrict__ It,
    const int* __restrict__ list, const int* __restrict__ cnt_in,
    unsigned long long* __restrict__ cand) {
  const int q = blockIdx.x >> 4;
  const int sg = blockIdx.x & 15;
  __shared__ float qv[DQ];
  if (threadIdx.x < DQ) qv[threadIdx.x] = Q[q * DQ + threadIdx.x];
  __syncthreads();
  const int s = threadIdx.x >> 4;
  const int it = threadIdx.x & 15;
  const int gs = sg * 16 + s;
  int n = cnt_in[q];
  if (n > CAP) n = CAP;
  unsigned long long out = 0ULL;
  if (gs < n) {
    const int chunk = list[q * CAP + gs];
    const int x = chunk * CHUNK + it;
    float a = 0.f;
#pragma unroll 8
    for (int d = 0; d < DQ; ++d) a = fmaf(qv[d], It[(size_t)d * XT + x], a);
    out = packkv(a, (unsigned)x);
  }
  cand[(size_t)q * NCAND + gs * CHUNK + it] = out;
}

// =================== K4: histogram-select top-100 (no 4096-wide sort) ===================
// s100 >= thr + DELTA => bin(v100) >= 128; bstar (max bin with suffix>=100) equals
// bin(v100) exactly (strictly-higher bins hold <=99 strictly-greater keys), so
// selecting bin >= bstar captures all top-100 keys; expected count ~100-106 << 512.
__global__ __launch_bounds__(1024) void k4_final(
    const unsigned long long* __restrict__ cand, const float* __restrict__ thrArr,
    float* __restrict__ out) {
  const int q = blockIdx.x;
  const int t = threadIdx.x;
  __shared__ int hist[K4BINS];
  __shared__ unsigned long long sel[K4SEL];
  __shared__ int scnt, bstar;
  hist[t] = 0;
  if (t < K4SEL) sel[t] = 0ULL;
  if (t == 0) { scnt = 0; bstar = 0; }
  const float base = thrArr[q];
  unsigned long long e[4];
  float vv[4];
#pragma unroll
  for (int i = 0; i < 4; ++i) {
    e[i] = cand[(size_t)q * NCAND + t + i * 1024];
    vv[i] = pk_val(e[i]);
  }
  __syncthreads();
#pragma unroll
  for (int i = 0; i < 4; ++i) {
    float d = (vv[i] - base) * 256.0f;
    int b = (d >= 1.0f) ? ((d < (float)(K4BINS - 1)) ? (int)d : (K4BINS - 1)) : 0;
    if (b > 0) atomicAdd(&hist[b], 1);  // NaN (zero key) and bin-0 skipped
  }
  __syncthreads();
  for (int off = 1; off < K4BINS; off <<= 1) {  // suffix sum over 1024 bins
    int v = (t + off < K4BINS) ? hist[t + off] : 0;
    __syncthreads();
    hist[t] += v;
    __syncthreads();
  }
  {
    bool p = hist[t] >= KTOP;
    bool pn = (t < K4BINS - 1) ? (hist[t + 1] >= KTOP) : false;
    if (p && !pn) bstar = t;  // unique boundary (suffix non-increasing)
  }
  __syncthreads();
  const int bs = bstar;
#pragma unroll
  for (int i = 0; i < 4; ++i) {
    float d = (vv[i] - base) * 256.0f;
    int b = (d >= 1.0f) ? ((d < (float)(K4BINS - 1)) ? (int)d : (K4BINS - 1)) : 0;
    if (b >= bs && e[i] != 0ULL) {
      int pos = atomicAdd(&scnt, 1);
      if (pos < K4SEL) sel[pos] = e[i];
    }
  }
  __syncthreads();
  bitonic_sort<K4SEL>(sel);
  for (int r = t; r < KTOP; r += 1024) {
    unsigned long long ee = sel[K4SEL - 1 - r];
    out[q * KTOP + r] = pk_val(ee);                       // topk_logits
    out[BQ * KTOP + q * KTOP + r] = (float)pk_id(ee);     // topk_item_ids
  }
}

extern "C" void kernel_launch(void* const* d_in, const int* in_sizes, int n_in,
                              void* d_out, int out_size, void* d_ws, size_t ws_size,
                              hipStream_t stream) {
  const float* Q = (const float*)d_in[0];   // [256,128]
  const float* It = (const float*)d_in[1];  // [128,1000000]
  float* out = (float*)d_out;               // [25600 logits][25600 ids]
  char* ws = (char*)d_ws;
  // ws layout (bytes):
  //   M      : 0          .. 32,014,336   (62528 x 256 bf16, CHUNK-MAJOR)
  //   ghist  : 32,014,336 .. +524,288     (256 x 512 int)
  //   thrArr : 32,538,624 .. +1,024
  //   list   : 32,539,648 .. +262,144
  //   cnt    : 32,801,792 .. +1,024
  //   norms  : 32,802,816 .. +1,024
  //   Qp     : 32,803,840 .. +65,536
  //   cand   : 33,554,432 .. +8,388,608
  unsigned short* M = (unsigned short*)ws;
  int* ghist = (int*)(ws + 32014336);
  float* thrArr = (float*)(ws + 32538624);
  int* list = (int*)(ws + 32539648);
  int* cnt = (int*)(ws + 32801792);
  float* norms = (float*)(ws + 32802816);
  unsigned short* Qp = (unsigned short*)(ws + 32803840);
  unsigned long long* cand = (unsigned long long*)(ws + 33554432);

  p0_qprep<<<dim3(BQ), dim3(DQ), 0, stream>>>(Q, Qp, norms, (uint4*)ghist);
  k1_filter<<<dim3(NBLK), dim3(256), 0, stream>>>(Qp, It, norms, M, ghist);
  k2b_thr<<<dim3(BQ), dim3(512), 0, stream>>>(ghist, norms, thrArr, cnt);
  k2c_emit<<<dim3(NBLK), dim3(256), 0, stream>>>(M, thrArr, list, cnt);
  k3_rescore<<<dim3(BQ * 16), dim3(256), 0, stream>>>(Q, It, list, cnt, cand);
  k4_final<<<dim3(BQ), dim3(1024), 0, stream>>>(cand, thrArr, out);
}